// Round 4
// baseline (344.175 us; speedup 1.0000x reference)
//
#include <hip/hip_runtime.h>

// LinearCrossAttention: B=16, N=4096, M=1024, C_in=C_cond=512, HIDDEN=512
#define KDIM 512

typedef __attribute__((ext_vector_type(8))) short bf16x8;
typedef __attribute__((ext_vector_type(4))) float f32x4;
typedef unsigned short u16;
typedef unsigned int u32;

static __device__ __forceinline__ u16 f2bf(float f) {
  u32 u = __builtin_bit_cast(u32, f);
  u32 r = u + 0x7fffu + ((u >> 16) & 1u);   // round-to-nearest-even
  return (u16)(r >> 16);
}

// ---------------------------------------------------------------------------
// prep: f32 -> bf16 (for Wkv), 8 elems/thread
// ---------------------------------------------------------------------------
__global__ __launch_bounds__(256) void cvt_f32_bf16(
    const float* __restrict__ src, u16* __restrict__ dst, int n8)
{
  int i = blockIdx.x * 256 + threadIdx.x;
  if (i >= n8) return;
  float4 a = *(const float4*)(src + (long)i * 8);
  float4 b = *(const float4*)(src + (long)i * 8 + 4);
  u32 w0 = (u32)f2bf(a.x) | ((u32)f2bf(a.y) << 16);
  u32 w1 = (u32)f2bf(a.z) | ((u32)f2bf(a.w) << 16);
  u32 w2 = (u32)f2bf(b.x) | ((u32)f2bf(b.y) << 16);
  u32 w3 = (u32)f2bf(b.z) | ((u32)f2bf(b.w) << 16);
  *(uint4*)(dst + (long)i * 8) = make_uint4(w0, w1, w2, w3);
}

// ---------------------------------------------------------------------------
// BM=512/BN=128/BK=32 pipelined GEMM.
// A: bf16 [*,512] row-major.  B: f32 [512,ldn] row-major (transposed+cvt to
// bf16 in LDS).  512 threads = 8 waves (4M x 2N), per-wave 128x64 out.
// Schedule: LDS double-buffered per K-step; depth-2 register pipeline
// (loads for step k+2 issued before MFMA of step k; ds_write of step k+1
// data gets a compiler-counted vmcnt with 6 loads still in flight — never
// drains to 0 in the main loop).  One barrier per K-step.
// LDS XOR-swizzle (T2): off16 = (row*32 + c) ^ ((row&7)<<3) — single
// ds_read_b128 fragments, <=2-way bank conflicts, 80 KB total.
// ---------------------------------------------------------------------------
#define AOFF(row, c16) ((((row) * 32) + (c16)) ^ (((row) & 7) << 3))

#define LOADA(dst, kt) { _Pragma("unroll") \
  for (int i_ = 0; i_ < 4; ++i_) \
    dst[i_] = *(const uint4*)(Ab + (long)(ar + i_ * 128) * KDIM + (kt) + ac * 8); }

#define LOADB(d0, d1, kt) { \
  d0 = *(const float4*)(Bb + (long)((kt) + kq2)     * ldn + nq * 4); \
  d1 = *(const float4*)(Bb + (long)((kt) + kq2 + 1) * ldn + nq * 4); }

#define STAGEA(src, base) { _Pragma("unroll") \
  for (int i_ = 0; i_ < 4; ++i_) \
    *(uint4*)&lds[(base) + AOFF(ar + i_ * 128, ac * 8)] = src[i_]; }

#define STAGEB(s0, s1, base) { \
  float q0_[4] = {s0.x, s0.y, s0.z, s0.w}; \
  float q1_[4] = {s1.x, s1.y, s1.z, s1.w}; \
  _Pragma("unroll") for (int j_ = 0; j_ < 4; ++j_) { \
    int n_ = nq * 4 + j_; \
    u32 w_ = (u32)f2bf(q0_[j_]) | ((u32)f2bf(q1_[j_]) << 16); \
    *(u32*)&lds[(base) + AOFF(n_, kq2)] = w_; } }

#define MFMA_STEP(abase, bbase) { \
  bf16x8 bfr_[4]; \
  _Pragma("unroll") for (int ni_ = 0; ni_ < 4; ++ni_) { \
    int n_ = wn * 64 + ni_ * 16 + lrow; \
    bfr_[ni_] = *(const bf16x8*)&lds[(bbase) + AOFF(n_, lkh * 8)]; } \
  __builtin_amdgcn_s_setprio(1); \
  _Pragma("unroll") for (int mi_ = 0; mi_ < 8; ++mi_) { \
    int rr_ = wm * 128 + mi_ * 16 + lrow; \
    bf16x8 af_ = *(const bf16x8*)&lds[(abase) + AOFF(rr_, lkh * 8)]; \
    _Pragma("unroll") for (int ni_ = 0; ni_ < 4; ++ni_) \
      acc[mi_][ni_] = __builtin_amdgcn_mfma_f32_16x16x32_bf16(af_, bfr_[ni_], acc[mi_][ni_], 0, 0, 0); } \
  __builtin_amdgcn_s_setprio(0); }

template<bool OUT_BF16, bool BIAS, bool CLUST>
__global__ __launch_bounds__(512, 2) void gemm_v2(
    const u16* __restrict__ Ap, long a_bstride,
    const float* __restrict__ Bp, long b_bstride,
    void* __restrict__ Op, long o_bstride,
    const float* __restrict__ bias, int ldn)
{
  // raw LDS: A buffers at u16-offset 0 and 16384, B at 32768 and 36864 (80 KB)
  __shared__ char RAW[81920];
  u16* lds = (u16*)RAW;

  int mt, nt, b;
  if constexpr (CLUST) {                 // K4: grid=512 1-D, batch pinned to XCD
    const int bx = blockIdx.x;
    const int idx = bx >> 3;
    b = (bx & 7) + 8 * (idx >> 5);
    nt = idx & 31;
    mt = 0;
  } else { mt = blockIdx.x; nt = blockIdx.y; b = blockIdx.z; }

  const long mtile = (long)mt * 512;
  const long ntile = (long)nt * 128;
  const u16* Ab = Ap + (long)b * a_bstride + mtile * KDIM;
  const float* Bb = Bp + (long)b * b_bstride + ntile;

  const int t = threadIdx.x;
  const int lane = t & 63, wv = t >> 6;
  const int wm = wv >> 1, wn = wv & 1;   // 4 x 2 wave grid
  const int lrow = lane & 15, lkh = lane >> 4;

  // staging maps
  const int ar = t >> 2, ac = t & 3;     // A: rows ar+128i, 16B chunk ac
  const int nq = t & 31;                 // B: 4-col group
  const int kq2 = (t >> 5) * 2;          // B: adjacent k-row pair

  f32x4 acc[8][4] = {};
  uint4 a0[4], a1[4];
  float4 b0a, b0b, b1a, b1b;

  // ---- prologue: fill both pipeline sets, stage step 0 ----
  LOADA(a0, 0)  LOADB(b0a, b0b, 0)
  LOADA(a1, 32) LOADB(b1a, b1b, 32)
  STAGEA(a0, 0) STAGEB(b0a, b0b, 32768)
  __syncthreads();

  for (int s2 = 0; s2 < 8; ++s2) {       // 16 K-steps, pairs (even uses buf0)
    const int kt = s2 * 64;
    const bool more = s2 < 7;
    // even step: compute buf0; prefetch k+2 into set0; stage set1 -> buf1
    if (more) { LOADA(a0, kt + 64) LOADB(b0a, b0b, kt + 64) }
    MFMA_STEP(0, 32768)
    STAGEA(a1, 16384) STAGEB(b1a, b1b, 36864)
    __syncthreads();
    // odd step: compute buf1; prefetch k+2 into set1; stage set0 -> buf0
    if (more) { LOADA(a1, kt + 96) LOADB(b1a, b1b, kt + 96) }
    MFMA_STEP(16384, 36864)
    if (more) {
      STAGEA(a0, 0) STAGEB(b0a, b0b, 32768)
      __syncthreads();
    }
  }

  // ---- epilogue: LDS transpose per mi-chunk -> contiguous vector stores ----
  float* ldsF = (float*)RAW;             // 64 x 132 f32 chunk (33.8 KB)
  const int L = t >> 3, seg = (t & 7) * 16;
  const int erow = wm * 16 + lkh * 4;
  const int ecol = wn * 64 + lrow;
  #pragma unroll
  for (int mi = 0; mi < 8; ++mi) {
    __syncthreads();                     // prev chunk (or K-loop tail) done
    #pragma unroll
    for (int ni = 0; ni < 4; ++ni)
      #pragma unroll
      for (int r = 0; r < 4; ++r)
        ldsF[(erow + r) * 132 + ecol + ni * 16] = acc[mi][ni][r];
    __syncthreads();
    const long gr = mtile + (L >> 4) * 128 + mi * 16 + (L & 15);
    float bv = 0.f;
    if constexpr (BIAS) bv = bias[gr];
    float v[16];
    #pragma unroll
    for (int j = 0; j < 16; ++j) v[j] = ldsF[L * 132 + seg + j] + bv;
    if constexpr (OUT_BF16) {
      u32 w[8];
      #pragma unroll
      for (int j = 0; j < 8; ++j)
        w[j] = (u32)f2bf(v[2 * j]) | ((u32)f2bf(v[2 * j + 1]) << 16);
      u16* dst = (u16*)Op + (long)b * o_bstride + gr * ldn + ntile + seg;
      *(uint4*)dst       = make_uint4(w[0], w[1], w[2], w[3]);
      *(uint4*)(dst + 8) = make_uint4(w[4], w[5], w[6], w[7]);
    } else {
      float* dst = (float*)Op + (long)b * o_bstride + gr * ldn + ntile + seg;
      *(float4*)dst        = make_float4(v[0],  v[1],  v[2],  v[3]);
      *(float4*)(dst + 4)  = make_float4(v[4],  v[5],  v[6],  v[7]);
      *(float4*)(dst + 8)  = make_float4(v[8],  v[9],  v[10], v[11]);
      *(float4*)(dst + 12) = make_float4(v[12], v[13], v[14], v[15]);
    }
  }
}

// ---------------------------------------------------------------------------
// K2: per (b,h): softmax over m of K rows, ctx[d][e] = sum_m Kexp[d][m]*V[e][m]
// ---------------------------------------------------------------------------
typedef __attribute__((ext_vector_type(8))) short bf16x8_t;
static __device__ __forceinline__ bf16x8 ld_frag2(const u16* p) {
  uint2 lo = *(const uint2*)p;
  uint2 hi = *(const uint2*)(p + 4);
  uint4 u = make_uint4(lo.x, lo.y, hi.x, hi.y);
  return __builtin_bit_cast(bf16x8, u);
}

__global__ __launch_bounds__(256, 2) void softmax_context(
    const u16* __restrict__ kv, float* __restrict__ ctx)
{
  constexpr int LDE = 132;
  __shared__ float rowmax[64], rowinv[64];
  __shared__ u16 Ke[64 * LDE];
  __shared__ u16 Vs[64 * LDE];
  __shared__ float pr[64 * 68];

  const int bh = blockIdx.x;
  const u16* Kr = kv + (long)(bh >> 3) * (1024 * 1024) + (long)(bh & 7) * (64 * 1024);
  const u16* Vr = Kr + 512 * 1024;

  const int t = threadIdx.x;
  const int lane = t & 63, wv = t >> 6;
  const int lrow = lane & 15, lkh = lane >> 4;
  const int d4 = t >> 2, q4 = t & 3;

  {
    const u16* row = Kr + d4 * 1024 + q4 * 256;
    float mx = -3e38f;
    for (int i = 0; i < 256; i += 8) {
      uint4 v = *(const uint4*)(row + i);
      u32 ws[4] = {v.x, v.y, v.z, v.w};
      #pragma unroll
      for (int j = 0; j < 4; ++j) {
        mx = fmaxf(mx, __builtin_bit_cast(float, ws[j] << 16));
        mx = fmaxf(mx, __builtin_bit_cast(float, ws[j] & 0xffff0000u));
      }
    }
    mx = fmaxf(mx, __shfl_xor(mx, 1));
    mx = fmaxf(mx, __shfl_xor(mx, 2));
    float s = 0.f;
    for (int i = 0; i < 256; i += 8) {
      uint4 v = *(const uint4*)(row + i);
      u32 ws[4] = {v.x, v.y, v.z, v.w};
      #pragma unroll
      for (int j = 0; j < 4; ++j) {
        s += __expf(__builtin_bit_cast(float, ws[j] << 16) - mx);
        s += __expf(__builtin_bit_cast(float, ws[j] & 0xffff0000u) - mx);
      }
    }
    s += __shfl_xor(s, 1);
    s += __shfl_xor(s, 2);
    if (q4 == 0) { rowmax[d4] = mx; rowinv[d4] = 1.f / s; }
  }
  __syncthreads();

  f32x4 cacc[4][4] = {};

  for (int mc = 0; mc < 8; ++mc) {
    {
      int dd = t >> 2, j = t & 3;
      int m0 = mc * 128 + j * 32;
      float mx = rowmax[dd], inv = rowinv[dd];
      const u16* src = Kr + dd * 1024 + m0;
      u16* dst = &Ke[dd * LDE + j * 32];
      #pragma unroll
      for (int cq = 0; cq < 4; ++cq) {
        uint4 v = *(const uint4*)(src + cq * 8);
        u32 in[4] = {v.x, v.y, v.z, v.w};
        u32 out[4];
        #pragma unroll
        for (int j2 = 0; j2 < 4; ++j2) {
          float lo = __builtin_bit_cast(float, in[j2] << 16);
          float hi = __builtin_bit_cast(float, in[j2] & 0xffff0000u);
          out[j2] = (u32)f2bf(__expf(lo - mx) * inv) |
                    ((u32)f2bf(__expf(hi - mx) * inv) << 16);
        }
        *(uint2*)(dst + cq * 8)     = make_uint2(out[0], out[1]);
        *(uint2*)(dst + cq * 8 + 4) = make_uint2(out[2], out[3]);
      }
      const u16* vsrc = Vr + dd * 1024 + m0;
      u16* vdst = &Vs[dd * LDE + j * 32];
      #pragma unroll
      for (int cq = 0; cq < 4; ++cq) {
        uint4 v = *(const uint4*)(vsrc + cq * 8);
        *(uint2*)(vdst + cq * 8)     = make_uint2(v.x, v.y);
        *(uint2*)(vdst + cq * 8 + 4) = make_uint2(v.z, v.w);
      }
    }
    __syncthreads();
    bf16x8 ka[4], vb[4];
    #pragma unroll
    for (int mi = 0; mi < 4; ++mi)
      ka[mi] = ld_frag2(&Ke[(mi * 16 + lrow) * LDE + wv * 32 + lkh * 8]);
    #pragma unroll
    for (int ni = 0; ni < 4; ++ni)
      vb[ni] = ld_frag2(&Vs[(ni * 16 + lrow) * LDE + wv * 32 + lkh * 8]);
    #pragma unroll
    for (int mi = 0; mi < 4; ++mi)
      #pragma unroll
      for (int ni = 0; ni < 4; ++ni)
        cacc[mi][ni] = __builtin_amdgcn_mfma_f32_16x16x32_bf16(ka[mi], vb[ni], cacc[mi][ni], 0, 0, 0);
    __syncthreads();
  }

  for (int w = 0; w < 4; ++w) {
    if (wv == w) {
      #pragma unroll
      for (int mi = 0; mi < 4; ++mi)
        #pragma unroll
        for (int ni = 0; ni < 4; ++ni)
          #pragma unroll
          for (int r = 0; r < 4; ++r) {
            float* p = &pr[(mi * 16 + lkh * 4 + r) * 68 + (ni * 16 + lrow)];
            float v = cacc[mi][ni][r];
            if (w == 0) *p = v; else *p += v;
          }
    }
    __syncthreads();
  }
  float* cg = ctx + (long)bh * 4096;
  for (int i = 0; i < 16; ++i) {
    int o = t + i * 256;
    cg[o] = 0.125f * pr[(o >> 6) * 68 + (o & 63)];  // fold q-scale
  }
}

// ---------------------------------------------------------------------------
// K3a: U[b][o][h*64+d] = sum_e Wo[o][h*64+e] * ctx[b,h,d,e]
// ---------------------------------------------------------------------------
__global__ __launch_bounds__(256) void compose_u(
    const float* __restrict__ ctx, const float* __restrict__ Wo, u16* __restrict__ U)
{
  __shared__ float cs[16 * 64];
  const int bh = blockIdx.x, dq = blockIdx.y;
  const int b = bh >> 3, h = bh & 7;
  const int t = threadIdx.x;
  const float* cgrp = ctx + (long)bh * 4096 + dq * 16 * 64;
  for (int i = t; i < 1024; i += 256) cs[i] = cgrp[i];
  __syncthreads();
  #pragma unroll
  for (int rep = 0; rep < 2; ++rep) {
    int o = rep * 256 + t;
    const float* wrow = Wo + (long)o * 512 + h * 64;
    float acc[16] = {};
    for (int e = 0; e < 64; ++e) {
      float w = wrow[e];
      #pragma unroll
      for (int dd = 0; dd < 16; ++dd) acc[dd] += w * cs[dd * 64 + e];
    }
    u16* urow = U + (long)b * (512 * 512) + (long)o * 512 + h * 64 + dq * 16;
    #pragma unroll
    for (int dd = 0; dd < 16; ++dd) urow[dd] = f2bf(acc[dd]);
  }
}

// ---------------------------------------------------------------------------
extern "C" void kernel_launch(void* const* d_in, const int* in_sizes, int n_in,
                              void* d_out, int out_size, void* d_ws, size_t ws_size,
                              hipStream_t stream)
{
  const float* x   = (const float*)d_in[0];  // [16, 512, 4096]
  const float* c   = (const float*)d_in[1];  // [16, 512, 1024]
  const float* Wq  = (const float*)d_in[2];  // [512, 512]
  const float* Wkv = (const float*)d_in[3];  // [1024, 512]
  const float* Wo  = (const float*)d_in[4];  // [512, 512]
  const float* bo  = (const float*)d_in[5];  // [512]

  // workspace layout (52.4 MB total)
  char* ws = (char*)d_ws;
  u16*   kv   = (u16*)ws;                      // 16*1024*1024 bf16 = 33.5 MB
  float* ctx  = (float*)(ws + 33554432);       // 16*8*64*64 f32    =  2.1 MB
  u16*   U    = (u16*)(ws + 35651584);         // 16*512*512 bf16   =  8.4 MB
  u16*   Weff = (u16*)(ws + 44040192);         // 16*512*512 bf16   =  8.4 MB
  u16*   Wkvb = (u16*)(ws + 44040192);         // 1 MB, overlaps Weff: consumed by K1
                                               // BEFORE K3b writes Weff

  // K0: Wkv f32 -> bf16
  cvt_f32_bf16<<<dim3(256), 256, 0, stream>>>(Wkv, Wkvb, 65536);
  // K1: kv[b] = Wkv @ c[b]   (MT=2, NT=8)
  gemm_v2<true, false, false><<<dim3(2, 8, 16), 512, 0, stream>>>(
      Wkvb, 0, c, 512L * 1024, kv, 1024L * 1024, nullptr, 1024);
  // K2: softmax + context
  softmax_context<<<dim3(128), 256, 0, stream>>>(kv, ctx);
  // K3a: U = scale * Wo_h @ ctx_h^T
  compose_u<<<dim3(128, 4), 256, 0, stream>>>(ctx, Wo, U);
  // K3b: Weff[b] = U[b] @ Wq   (MT=1, NT=4)
  gemm_v2<true, false, false><<<dim3(1, 4, 16), 512, 0, stream>>>(
      U, 512L * 512, Wq, 0, Weff, 512L * 512, nullptr, 512);
  // K4: Y[b] = Weff[b] @ x[b] + bo   (batch-clustered XCD decode, 1-D grid)
  gemm_v2<false, true, true><<<dim3(512), 512, 0, stream>>>(
      Weff, 512L * 512, x, 512L * 4096, d_out, 512L * 4096, bo, 4096);
}

// Round 5
// 195.439 us; speedup vs baseline: 1.7610x; 1.7610x over previous
//
#include <hip/hip_runtime.h>

// LinearCrossAttention: B=16, N=4096, M=1024, C_in=C_cond=512, HIDDEN=512
#define KDIM 512

typedef __attribute__((ext_vector_type(8))) short bf16x8;
typedef __attribute__((ext_vector_type(4))) float f32x4;
typedef unsigned short u16;
typedef unsigned int u32;

static __device__ __forceinline__ u16 f2bf(float f) {
  u32 u = __builtin_bit_cast(u32, f);
  u32 r = u + 0x7fffu + ((u >> 16) & 1u);   // round-to-nearest-even
  return (u16)(r >> 16);
}
static __device__ __forceinline__ bf16x8 ld_frag(const u16* p) {
  uint2 lo = *(const uint2*)p;
  uint2 hi = *(const uint2*)(p + 4);
  uint4 u = make_uint4(lo.x, lo.y, hi.x, hi.y);
  return __builtin_bit_cast(bf16x8, u);
}

// ---------------------------------------------------------------------------
// prep: f32 -> bf16 (for Wkv), 8 elems/thread
// ---------------------------------------------------------------------------
__global__ __launch_bounds__(256) void cvt_f32_bf16(
    const float* __restrict__ src, u16* __restrict__ dst, int n8)
{
  int i = blockIdx.x * 256 + threadIdx.x;
  if (i >= n8) return;
  float4 a = *(const float4*)(src + (long)i * 8);
  float4 b = *(const float4*)(src + (long)i * 8 + 4);
  u32 w0 = (u32)f2bf(a.x) | ((u32)f2bf(a.y) << 16);
  u32 w1 = (u32)f2bf(a.z) | ((u32)f2bf(a.w) << 16);
  u32 w2 = (u32)f2bf(b.x) | ((u32)f2bf(b.y) << 16);
  u32 w3 = (u32)f2bf(b.z) | ((u32)f2bf(b.w) << 16);
  *(uint4*)(dst + (long)i * 8) = make_uint4(w0, w1, w2, w3);
}

// ---------------------------------------------------------------------------
// BM=256 / BN=128 / BK=64 GEMM, 512 threads = 8 waves (4M x 2N), per-wave
// 64x64 output (acc = 4x4 frags = 64 VGPR).  Sized for 2 blocks/CU:
// LDS 52 KB, VGPR capped at 128 via __launch_bounds__(512,4) -> 16 waves/CU.
// Two resident blocks interleave their stage/drain bubbles (the round-3
// single-block lockstep was the limiter).
// A: bf16 [*,512] row-major.  B: f32 [512,ldn] row-major, transposed+cvt to
// bf16 in LDS.  Depth-1 register prefetch, 2-phase, 2 barriers/K-step.
// 1-D grid, mt INNERMOST so the MT blocks sharing a B-slice are dispatched
// adjacently (second read = L3 hit).
// ---------------------------------------------------------------------------
template<bool OUT_BF16, bool BIAS, int MT, int NT>
__global__ __launch_bounds__(512, 4) void gemm_v3(
    const u16* __restrict__ Ap, long a_bstride,
    const float* __restrict__ Bp, long b_bstride,
    void* __restrict__ Op, long o_bstride,
    const float* __restrict__ bias, int ldn)
{
  constexpr int LDT = 68;                  // 64 + 4 pad: proven 0-conflict
  __shared__ u16 Ash[256 * LDT];           // 34.8 KB
  __shared__ u16 Bsh[128 * LDT];           // 17.4 KB

  const int d = blockIdx.x;
  const int mt = d % MT;
  const int nt = (d / MT) % NT;
  const int b  = d / (MT * NT);
  const long mtile = (long)mt * 256;
  const long ntile = (long)nt * 128;
  const u16* Ab = Ap + (long)b * a_bstride + mtile * KDIM;
  const float* Bb = Bp + (long)b * b_bstride + ntile;

  const int t = threadIdx.x;
  const int lane = t & 63, wv = t >> 6;
  const int wm = wv >> 1, wn = wv & 1;     // 4 x 2 wave grid
  const int lrow = lane & 15, lkh = lane >> 4;

  // staging maps
  const int ar = t >> 3, ac8 = t & 7;      // A: rows ar, ar+64, ...; 16B chunk ac8
  const int nq = t & 31;                   // B: 4-col group (128 cols)
  const int kq = t >> 5;                   // B: 4-row group (64 rows)

  f32x4 acc[4][4] = {};
  uint4 pa[4];
  float4 pb[4];

  #define LOADA_V3(kt) { _Pragma("unroll") \
    for (int i_ = 0; i_ < 4; ++i_) \
      pa[i_] = *(const uint4*)(Ab + (long)(ar + i_ * 64) * KDIM + (kt) + ac8 * 8); }

  #define LOADB_V3(kt) { _Pragma("unroll") \
    for (int k_ = 0; k_ < 4; ++k_) \
      pb[k_] = *(const float4*)(Bb + (long)((kt) + kq * 4 + k_) * ldn + nq * 4); }

  #define STAGE_V3() { \
    _Pragma("unroll") for (int i_ = 0; i_ < 4; ++i_) { \
      u16* dst_ = &Ash[(ar + i_ * 64) * LDT + ac8 * 8]; \
      *(uint2*)dst_       = make_uint2(pa[i_].x, pa[i_].y); \
      *(uint2*)(dst_ + 4) = make_uint2(pa[i_].z, pa[i_].w); } \
    float q0_[4] = {pb[0].x, pb[0].y, pb[0].z, pb[0].w}; \
    float q1_[4] = {pb[1].x, pb[1].y, pb[1].z, pb[1].w}; \
    float q2_[4] = {pb[2].x, pb[2].y, pb[2].z, pb[2].w}; \
    float q3_[4] = {pb[3].x, pb[3].y, pb[3].z, pb[3].w}; \
    _Pragma("unroll") for (int j_ = 0; j_ < 4; ++j_) { \
      u32 w0_ = (u32)f2bf(q0_[j_]) | ((u32)f2bf(q1_[j_]) << 16); \
      u32 w1_ = (u32)f2bf(q2_[j_]) | ((u32)f2bf(q3_[j_]) << 16); \
      *(uint2*)&Bsh[(nq * 4 + j_) * LDT + kq * 4] = make_uint2(w0_, w1_); } }

  // ---- prologue ----
  LOADA_V3(0) LOADB_V3(0)
  STAGE_V3()
  __syncthreads();

  for (int s = 0; s < 8; ++s) {
    if (s < 7) { LOADA_V3((s + 1) * 64) LOADB_V3((s + 1) * 64) }
    // ---- MFMA from LDS ----
    #pragma unroll
    for (int kk = 0; kk < 2; ++kk) {
      bf16x8 bfr[4];
      #pragma unroll
      for (int ni = 0; ni < 4; ++ni)
        bfr[ni] = ld_frag(&Bsh[(wn * 64 + ni * 16 + lrow) * LDT + kk * 32 + lkh * 8]);
      #pragma unroll
      for (int mi = 0; mi < 4; ++mi) {
        bf16x8 af = ld_frag(&Ash[(wm * 64 + mi * 16 + lrow) * LDT + kk * 32 + lkh * 8]);
        #pragma unroll
        for (int ni = 0; ni < 4; ++ni)
          acc[mi][ni] = __builtin_amdgcn_mfma_f32_16x16x32_bf16(af, bfr[ni], acc[mi][ni], 0, 0, 0);
      }
    }
    __syncthreads();
    if (s < 7) {
      STAGE_V3()
      __syncthreads();
    }
  }

  // ---- epilogue: scalar stores, 16 lanes x 4B = 64B contiguous per instr ----
  #pragma unroll
  for (int mi = 0; mi < 4; ++mi) {
    #pragma unroll
    for (int r = 0; r < 4; ++r) {
      long gr = mtile + wm * 64 + mi * 16 + lkh * 4 + r;
      float bv = 0.0f;
      if constexpr (BIAS) bv = bias[gr];
      #pragma unroll
      for (int ni = 0; ni < 4; ++ni) {
        long gc = ntile + wn * 64 + ni * 16 + lrow;
        float v = acc[mi][ni][r] + bv;
        if constexpr (OUT_BF16)
          ((u16*)Op)[(long)b * o_bstride + gr * ldn + gc] = f2bf(v);
        else
          ((float*)Op)[(long)b * o_bstride + gr * ldn + gc] = v;
      }
    }
  }
  #undef LOADA_V3
  #undef LOADB_V3
  #undef STAGE_V3
}

// ---------------------------------------------------------------------------
// K2: per (b,h): softmax over m of K rows, ctx[d][e] = sum_m Kexp[d][m]*V[e][m]
// ---------------------------------------------------------------------------
__global__ __launch_bounds__(256, 2) void softmax_context(
    const u16* __restrict__ kv, float* __restrict__ ctx)
{
  constexpr int LDE = 132;
  __shared__ float rowmax[64], rowinv[64];
  __shared__ u16 Ke[64 * LDE];
  __shared__ u16 Vs[64 * LDE];
  __shared__ float pr[64 * 68];

  const int bh = blockIdx.x;
  const u16* Kr = kv + (long)(bh >> 3) * (1024 * 1024) + (long)(bh & 7) * (64 * 1024);
  const u16* Vr = Kr + 512 * 1024;

  const int t = threadIdx.x;
  const int lane = t & 63, wv = t >> 6;
  const int lrow = lane & 15, lkh = lane >> 4;
  const int d4 = t >> 2, q4 = t & 3;

  {
    const u16* row = Kr + d4 * 1024 + q4 * 256;
    float mx = -3e38f;
    for (int i = 0; i < 256; i += 8) {
      uint4 v = *(const uint4*)(row + i);
      u32 ws[4] = {v.x, v.y, v.z, v.w};
      #pragma unroll
      for (int j = 0; j < 4; ++j) {
        mx = fmaxf(mx, __builtin_bit_cast(float, ws[j] << 16));
        mx = fmaxf(mx, __builtin_bit_cast(float, ws[j] & 0xffff0000u));
      }
    }
    mx = fmaxf(mx, __shfl_xor(mx, 1));
    mx = fmaxf(mx, __shfl_xor(mx, 2));
    float s = 0.f;
    for (int i = 0; i < 256; i += 8) {
      uint4 v = *(const uint4*)(row + i);
      u32 ws[4] = {v.x, v.y, v.z, v.w};
      #pragma unroll
      for (int j = 0; j < 4; ++j) {
        s += __expf(__builtin_bit_cast(float, ws[j] << 16) - mx);
        s += __expf(__builtin_bit_cast(float, ws[j] & 0xffff0000u) - mx);
      }
    }
    s += __shfl_xor(s, 1);
    s += __shfl_xor(s, 2);
    if (q4 == 0) { rowmax[d4] = mx; rowinv[d4] = 1.f / s; }
  }
  __syncthreads();

  f32x4 cacc[4][4] = {};

  for (int mc = 0; mc < 8; ++mc) {
    {
      int dd = t >> 2, j = t & 3;
      int m0 = mc * 128 + j * 32;
      float mx = rowmax[dd], inv = rowinv[dd];
      const u16* src = Kr + dd * 1024 + m0;
      u16* dst = &Ke[dd * LDE + j * 32];
      #pragma unroll
      for (int cq = 0; cq < 4; ++cq) {
        uint4 v = *(const uint4*)(src + cq * 8);
        u32 in[4] = {v.x, v.y, v.z, v.w};
        u32 out[4];
        #pragma unroll
        for (int j2 = 0; j2 < 4; ++j2) {
          float lo = __builtin_bit_cast(float, in[j2] << 16);
          float hi = __builtin_bit_cast(float, in[j2] & 0xffff0000u);
          out[j2] = (u32)f2bf(__expf(lo - mx) * inv) |
                    ((u32)f2bf(__expf(hi - mx) * inv) << 16);
        }
        *(uint2*)(dst + cq * 8)     = make_uint2(out[0], out[1]);
        *(uint2*)(dst + cq * 8 + 4) = make_uint2(out[2], out[3]);
      }
      const u16* vsrc = Vr + dd * 1024 + m0;
      u16* vdst = &Vs[dd * LDE + j * 32];
      #pragma unroll
      for (int cq = 0; cq < 4; ++cq) {
        uint4 v = *(const uint4*)(vsrc + cq * 8);
        *(uint2*)(vdst + cq * 8)     = make_uint2(v.x, v.y);
        *(uint2*)(vdst + cq * 8 + 4) = make_uint2(v.z, v.w);
      }
    }
    __syncthreads();
    bf16x8 ka[4], vb[4];
    #pragma unroll
    for (int mi = 0; mi < 4; ++mi)
      ka[mi] = ld_frag(&Ke[(mi * 16 + lrow) * LDE + wv * 32 + lkh * 8]);
    #pragma unroll
    for (int ni = 0; ni < 4; ++ni)
      vb[ni] = ld_frag(&Vs[(ni * 16 + lrow) * LDE + wv * 32 + lkh * 8]);
    #pragma unroll
    for (int mi = 0; mi < 4; ++mi)
      #pragma unroll
      for (int ni = 0; ni < 4; ++ni)
        cacc[mi][ni] = __builtin_amdgcn_mfma_f32_16x16x32_bf16(ka[mi], vb[ni], cacc[mi][ni], 0, 0, 0);
    __syncthreads();
  }

  for (int w = 0; w < 4; ++w) {
    if (wv == w) {
      #pragma unroll
      for (int mi = 0; mi < 4; ++mi)
        #pragma unroll
        for (int ni = 0; ni < 4; ++ni)
          #pragma unroll
          for (int r = 0; r < 4; ++r) {
            float* p = &pr[(mi * 16 + lkh * 4 + r) * 68 + (ni * 16 + lrow)];
            float v = cacc[mi][ni][r];
            if (w == 0) *p = v; else *p += v;
          }
    }
    __syncthreads();
  }
  float* cg = ctx + (long)bh * 4096;
  for (int i = 0; i < 16; ++i) {
    int o = t + i * 256;
    cg[o] = 0.125f * pr[(o >> 6) * 68 + (o & 63)];  // fold q-scale
  }
}

// ---------------------------------------------------------------------------
// K3a: U[b][o][h*64+d] = sum_e Wo[o][h*64+e] * ctx[b,h,d,e]
// ---------------------------------------------------------------------------
__global__ __launch_bounds__(256) void compose_u(
    const float* __restrict__ ctx, const float* __restrict__ Wo, u16* __restrict__ U)
{
  __shared__ float cs[16 * 64];
  const int bh = blockIdx.x, dq = blockIdx.y;
  const int b = bh >> 3, h = bh & 7;
  const int t = threadIdx.x;
  const float* cgrp = ctx + (long)bh * 4096 + dq * 16 * 64;
  for (int i = t; i < 1024; i += 256) cs[i] = cgrp[i];
  __syncthreads();
  #pragma unroll
  for (int rep = 0; rep < 2; ++rep) {
    int o = rep * 256 + t;
    const float* wrow = Wo + (long)o * 512 + h * 64;
    float acc[16] = {};
    for (int e = 0; e < 64; ++e) {
      float w = wrow[e];
      #pragma unroll
      for (int dd = 0; dd < 16; ++dd) acc[dd] += w * cs[dd * 64 + e];
    }
    u16* urow = U + (long)b * (512 * 512) + (long)o * 512 + h * 64 + dq * 16;
    #pragma unroll
    for (int dd = 0; dd < 16; ++dd) urow[dd] = f2bf(acc[dd]);
  }
}

// ---------------------------------------------------------------------------
extern "C" void kernel_launch(void* const* d_in, const int* in_sizes, int n_in,
                              void* d_out, int out_size, void* d_ws, size_t ws_size,
                              hipStream_t stream)
{
  const float* x   = (const float*)d_in[0];  // [16, 512, 4096]
  const float* c   = (const float*)d_in[1];  // [16, 512, 1024]
  const float* Wq  = (const float*)d_in[2];  // [512, 512]
  const float* Wkv = (const float*)d_in[3];  // [1024, 512]
  const float* Wo  = (const float*)d_in[4];  // [512, 512]
  const float* bo  = (const float*)d_in[5];  // [512]

  // workspace layout (52.4 MB total)
  char* ws = (char*)d_ws;
  u16*   kv   = (u16*)ws;                      // 16*1024*1024 bf16 = 33.5 MB
  float* ctx  = (float*)(ws + 33554432);       // 16*8*64*64 f32    =  2.1 MB
  u16*   U    = (u16*)(ws + 35651584);         // 16*512*512 bf16   =  8.4 MB
  u16*   Weff = (u16*)(ws + 44040192);         // 16*512*512 bf16   =  8.4 MB
  u16*   Wkvb = (u16*)(ws + 44040192);         // 1 MB, overlaps Weff: consumed by K1
                                               // BEFORE K3b writes Weff

  // K0: Wkv f32 -> bf16
  cvt_f32_bf16<<<dim3(256), 256, 0, stream>>>(Wkv, Wkvb, 65536);
  // K1: kv[b] = Wkv @ c[b]      MT=4, NT=8  -> 512 blocks (2/CU)
  gemm_v3<true, false, 4, 8><<<dim3(4 * 8 * 16), 512, 0, stream>>>(
      Wkvb, 0, c, 512L * 1024, kv, 1024L * 1024, nullptr, 1024);
  // K2: softmax + context
  softmax_context<<<dim3(128), 256, 0, stream>>>(kv, ctx);
  // K3a: U = scale * Wo_h @ ctx_h^T
  compose_u<<<dim3(128, 4), 256, 0, stream>>>(ctx, Wo, U);
  // K3b: Weff[b] = U[b] @ Wq    MT=2, NT=4  -> 128 blocks
  gemm_v3<true, false, 2, 4><<<dim3(2 * 4 * 16), 512, 0, stream>>>(
      U, 512L * 512, Wq, 0, Weff, 512L * 512, nullptr, 512);
  // K4: Y[b] = Weff[b] @ x[b] + bo   MT=2, NT=32 -> 1024 blocks (2/CU)
  gemm_v3<false, true, 2, 32><<<dim3(2 * 32 * 16), 512, 0, stream>>>(
      Weff, 512L * 512, x, 512L * 4096, d_out, 512L * 4096, bo, 4096);
}